// Round 1
// baseline (376.472 us; speedup 1.0000x reference)
//
#include <hip/hip_runtime.h>
#include <stdint.h>

typedef _Float16 half8 __attribute__((ext_vector_type(8)));
typedef float floatx16 __attribute__((ext_vector_type(16)));
typedef unsigned long long u64;

#define ALPHA_ 1.0f
#define BETA_ 0.25f
#define NUM_EMBEDS 8192
#define EMBED_DIM 512
#define B_ 32
#define T_ 256
#define N_TOK 8192
#define THR_GAP 2e-3f

// ---------------- ws layout (bytes) ----------------
// wexact   @ 0        (64 KB)  u64 packed exact min: monokey<<32 | code
// cnorm    @ 65536    (32 KB)  ||c||^2
// counts   @ 98304    (32 KB)
// sse      @ 131072   (4 B)
// nflag    @ 131076   (4 B)
// worklist @ 131080   (32 KB)
// slot_m1  @ 1  MB    (2 MB)   u64 [32 chunks][8192 tok] block min1 key
// slot_d   @ 5  MB    (512 KB) f16 [32][8192] (min2 - min1) delta
// cb_i     @ 6  MB    (16 MB)  f16 h/m interleaved codebook [k][d]
// zt_i     @ 22 MB    (16 MB)  f16 h/m interleaved -2*z^T [n][d]
// ---------------------------------------------------
// interleaved row layout: row*1024 + grp*16 + plane*8  (grp = d/8, plane 0=h 1=m*2048)

typedef __attribute__((address_space(1))) const void ga_void;
typedef __attribute__((address_space(3))) void ls_void;
__device__ __forceinline__ void gl_lds16(const void* g, void* l) {
    __builtin_amdgcn_global_load_lds((ga_void*)g, (ls_void*)l, 16, 0, 0);
}

__device__ __forceinline__ uint32_t mono(float s) {
    uint32_t u = __float_as_uint(s);
    return (u & 0x80000000u) ? ~u : (u | 0x80000000u);
}
__device__ __forceinline__ float unmono(uint32_t v) {
    return __uint_as_float((v & 0x80000000u) ? (v ^ 0x80000000u) : ~v);
}

__global__ void pack_cb_kernel(const float* __restrict__ cb, _Float16* __restrict__ ci,
                               float* __restrict__ cnorm) {
    int row = blockIdx.x * 4 + (threadIdx.x >> 6);
    int lane = threadIdx.x & 63;
    const float* src = cb + (size_t)row * EMBED_DIM + lane * 8;
    float4 v0 = *(const float4*)src;
    float4 v1 = *(const float4*)(src + 4);
    float x[8] = {v0.x, v0.y, v0.z, v0.w, v1.x, v1.y, v1.z, v1.w};
    half8 hh, mm;
    float s = 0.f;
#pragma unroll
    for (int j = 0; j < 8; ++j) {
        s += x[j] * x[j];
        _Float16 hv = (_Float16)x[j];
        hh[j] = hv;
        mm[j] = (_Float16)((x[j] - (float)hv) * 2048.0f);
    }
    _Float16* dst = ci + (size_t)row * 1024 + lane * 16;
    *(half8*)dst = hh;
    *(half8*)(dst + 8) = mm;
#pragma unroll
    for (int d = 32; d; d >>= 1) s += __shfl_xor(s, d, 64);
    if (lane == 0) cnorm[row] = s;
}

__global__ void pack_z_kernel(const float* __restrict__ z, _Float16* __restrict__ zi) {
    int tid = threadIdx.x;
    int lane = tid & 63, ds = tid >> 6;
    int b = blockIdx.x >> 2;
    int t = ((blockIdx.x & 3) << 6) + lane;
    size_t n = (size_t)b * T_ + t;
    for (int g = 0; g < 16; ++g) {
        int d0 = g * 32 + ds * 8;
        const float* src = z + ((size_t)b * EMBED_DIM + d0) * T_ + t;
        half8 hh, mm;
#pragma unroll
        for (int j = 0; j < 8; ++j) {
            float x = -2.0f * src[(size_t)j * T_];
            _Float16 hv = (_Float16)x;
            hh[j] = hv;
            mm[j] = (_Float16)((x - (float)hv) * 2048.0f);
        }
        _Float16* dst = zi + n * 1024 + (size_t)(g * 4 + ds) * 16;
        *(half8*)dst = hh;
        *(half8*)(dst + 8) = mm;
    }
}

// ---- pass 1: 2-plane argmin GEMM, 256 codes x 128 tokens, 8 waves, BK=32,
//      2 phases per K-tile (barrier-pair + setprio role-split schedule) ----
#define MFMA16(a, b, c) __builtin_amdgcn_mfma_f32_32x32x16_f16(a, b, c, 0, 0, 0)

__global__ __launch_bounds__(512, 2) void argmin_kernel(
    const _Float16* __restrict__ cb_i, const _Float16* __restrict__ zt_i,
    const float* __restrict__ cnorm, u64* __restrict__ slot_m1,
    _Float16* __restrict__ slot_d) {
    // unified staging buffer: [buf][ A: 256 rows | B: 128 rows ] x 64 halves/row
    __shared__ alignas(16) _Float16 Sm[2][24576];  // 96 KB
    __shared__ u64 sK[3][128];
    __shared__ float sV1[3][128], sV2[3][128];

    const int tid = threadIdx.x;
    const int l = tid & 63;
    const int wv = tid >> 6;       // 0..7
    const int l31 = l & 31;
    const int hf = l >> 5;
    const int wm = wv >> 1;        // 0..3  code quarter
    const int wn = wv & 1;         // 0..1  token half
    const int n0 = blockIdx.x * 128;
    const int c0 = blockIdx.y * 256;

    // ---- staging setup: 48 chunks of 8 rows x 128 B (A: 0..31, B: 32..47);
    //      wave wv owns chunks 6wv..6wv+5; LDS offset = chunk*512 halves ----
    const int srow = l >> 3;
    const int sseg = (l & 7) ^ srow;  // XOR swizzle via pre-swizzled global src
    const _Float16* gsrc[6];
#pragma unroll
    for (int j = 0; j < 6; ++j) {
        int c = wv * 6 + j;
        gsrc[j] = (c < 32)
                      ? cb_i + (size_t)(c0 + c * 8 + srow) * 1024 + sseg * 8
                      : zt_i + (size_t)(n0 + (c - 32) * 8 + srow) * 1024 + sseg * 8;
    }
    const int sloff = wv * 3072;  // halves

    floatx16 acc1[2][2], acc2[2][2];
#pragma unroll
    for (int a = 0; a < 2; ++a)
#pragma unroll
        for (int b = 0; b < 2; ++b)
#pragma unroll
            for (int r = 0; r < 16; ++r) { acc1[a][b][r] = 0.f; acc2[a][b][r] = 0.f; }

    const int rs = l31 & 7;
    // granule offsets (halves) for (kk, plane): ((2*(kk*2+hf)+pl) ^ rs) * 8
    const int goh0 = ((2 * hf) ^ rs) * 8;
    const int gom0 = ((2 * hf + 1) ^ rs) * 8;
    const int goh1 = ((4 + 2 * hf) ^ rs) * 8;
    const int gom1 = ((4 + 2 * hf + 1) ^ rs) * 8;
    const int aoff = (wm * 64 + l31) * 64;           // A rows
    const int boff = 16384 + (wn * 64 + l31) * 64;   // B rows

    // ---- prologue: stage K-tile 0 into buf 0 ----
#pragma unroll
    for (int j = 0; j < 6; ++j) gl_lds16(gsrc[j], &Sm[0][sloff + j * 512]);
    asm volatile("s_waitcnt vmcnt(0)" ::: "memory");
    __builtin_amdgcn_s_barrier();

    for (int t = 0; t < 16; ++t) {
        const int p = t & 1;
        const _Float16* Ap = &Sm[0][0] + p * 24576 + aoff;
        const _Float16* Bp = &Sm[0][0] + p * 24576 + boff;
        _Float16* snx = &Sm[0][0] + (p ^ 1) * 24576 + sloff;
        // ================= phase 0 (kk=0) =================
        {
            half8 Ah0 = *(const half8*)(Ap + goh0);
            half8 Am0 = *(const half8*)(Ap + gom0);
            half8 Ah1 = *(const half8*)(Ap + 2048 + goh0);
            half8 Am1 = *(const half8*)(Ap + 2048 + gom0);
            half8 Bh0 = *(const half8*)(Bp + goh0);
            half8 Bm0 = *(const half8*)(Bp + gom0);
            half8 Bh1 = *(const half8*)(Bp + 2048 + goh0);
            half8 Bm1 = *(const half8*)(Bp + 2048 + gom0);
            if (t < 15) {
#pragma unroll
                for (int j = 0; j < 6; ++j)
                    gl_lds16(gsrc[j] + (size_t)(t + 1) * 64, snx + j * 512);
            }
            __builtin_amdgcn_s_barrier();
            asm volatile("s_waitcnt lgkmcnt(0)" ::: "memory");
            __builtin_amdgcn_sched_barrier(0);
            __builtin_amdgcn_s_setprio(1);
            acc1[0][0] = MFMA16(Ah0, Bh0, acc1[0][0]);
            acc2[0][0] = MFMA16(Ah0, Bm0, acc2[0][0]);
            acc2[0][0] = MFMA16(Am0, Bh0, acc2[0][0]);
            acc1[0][1] = MFMA16(Ah0, Bh1, acc1[0][1]);
            acc2[0][1] = MFMA16(Ah0, Bm1, acc2[0][1]);
            acc2[0][1] = MFMA16(Am0, Bh1, acc2[0][1]);
            acc1[1][0] = MFMA16(Ah1, Bh0, acc1[1][0]);
            acc2[1][0] = MFMA16(Ah1, Bm0, acc2[1][0]);
            acc2[1][0] = MFMA16(Am1, Bh0, acc2[1][0]);
            acc1[1][1] = MFMA16(Ah1, Bh1, acc1[1][1]);
            acc2[1][1] = MFMA16(Ah1, Bm1, acc2[1][1]);
            acc2[1][1] = MFMA16(Am1, Bh1, acc2[1][1]);
            __builtin_amdgcn_s_setprio(0);
            __builtin_amdgcn_s_barrier();
        }
        // ================= phase 1 (kk=1) =================
        {
            half8 Ah0 = *(const half8*)(Ap + goh1);
            half8 Am0 = *(const half8*)(Ap + gom1);
            half8 Ah1 = *(const half8*)(Ap + 2048 + goh1);
            half8 Am1 = *(const half8*)(Ap + 2048 + gom1);
            half8 Bh0 = *(const half8*)(Bp + goh1);
            half8 Bm0 = *(const half8*)(Bp + gom1);
            half8 Bh1 = *(const half8*)(Bp + 2048 + goh1);
            half8 Bm1 = *(const half8*)(Bp + 2048 + gom1);
            __builtin_amdgcn_s_barrier();
            asm volatile("s_waitcnt lgkmcnt(0)" ::: "memory");
            __builtin_amdgcn_sched_barrier(0);
            __builtin_amdgcn_s_setprio(1);
            acc1[0][0] = MFMA16(Ah0, Bh0, acc1[0][0]);
            acc2[0][0] = MFMA16(Ah0, Bm0, acc2[0][0]);
            acc2[0][0] = MFMA16(Am0, Bh0, acc2[0][0]);
            acc1[0][1] = MFMA16(Ah0, Bh1, acc1[0][1]);
            acc2[0][1] = MFMA16(Ah0, Bm1, acc2[0][1]);
            acc2[0][1] = MFMA16(Am0, Bh1, acc2[0][1]);
            acc1[1][0] = MFMA16(Ah1, Bh0, acc1[1][0]);
            acc2[1][0] = MFMA16(Ah1, Bm0, acc2[1][0]);
            acc2[1][0] = MFMA16(Am1, Bh0, acc2[1][0]);
            acc1[1][1] = MFMA16(Ah1, Bh1, acc1[1][1]);
            acc2[1][1] = MFMA16(Ah1, Bm1, acc2[1][1]);
            acc2[1][1] = MFMA16(Am1, Bh1, acc2[1][1]);
            __builtin_amdgcn_s_setprio(0);
            asm volatile("s_waitcnt vmcnt(0)" ::: "memory");  // next tile staged
            __builtin_amdgcn_s_barrier();
        }
    }

    // epilogue: per (lane,qi) -> one token, this wave covers 64 codes (wm quarter)
    u64 km[2]; float kv1[2], kv2[2];
#pragma unroll
    for (int qi = 0; qi < 2; ++qi) {
        u64 m1k = ~0ULL;
        float m1v = 3.4e38f, m2 = 3.4e38f;
#pragma unroll
        for (int ti = 0; ti < 2; ++ti)
#pragma unroll
            for (int g = 0; g < 4; ++g) {
                const int cb4 = c0 + wm * 64 + ti * 32 + g * 8 + hf * 4;
                float4 cn = *(const float4*)(cnorm + cb4);
                const floatx16& A1 = acc1[ti][qi];
                const floatx16& A2 = acc2[ti][qi];
                float sv[4] = {cn.x + A1[g * 4 + 0] + A2[g * 4 + 0] * (1.0f / 2048.0f),
                               cn.y + A1[g * 4 + 1] + A2[g * 4 + 1] * (1.0f / 2048.0f),
                               cn.z + A1[g * 4 + 2] + A2[g * 4 + 2] * (1.0f / 2048.0f),
                               cn.w + A1[g * 4 + 3] + A2[g * 4 + 3] * (1.0f / 2048.0f)};
#pragma unroll
                for (int q = 0; q < 4; ++q) {
                    u64 key = ((u64)mono(sv[q]) << 32) | (uint32_t)(cb4 + q);
                    if (key < m1k) { m2 = m1v; m1v = sv[q]; m1k = key; }
                    else m2 = fminf(m2, sv[q]);
                }
            }
        // merge across the hf pair (same token, other half of code m%8)
        u64 ok = __shfl_xor(m1k, 32, 64);
        float ov = __shfl_xor(m1v, 32, 64);
        float om2 = __shfl_xor(m2, 32, 64);
        if (ok < m1k) { m2 = fminf(fminf(m2, om2), m1v); m1v = ov; m1k = ok; }
        else m2 = fminf(fminf(m2, om2), ov);
        km[qi] = m1k; kv1[qi] = m1v; kv2[qi] = m2;
    }
    // cross-wave merge: wm=1..3 publish, wm=0 merges + stores
    if (wm != 0 && hf == 0) {
#pragma unroll
        for (int qi = 0; qi < 2; ++qi) {
            int idx = wn * 64 + qi * 32 + l31;
            sK[wm - 1][idx] = km[qi]; sV1[wm - 1][idx] = kv1[qi]; sV2[wm - 1][idx] = kv2[qi];
        }
    }
    __syncthreads();
    if (wm == 0 && hf == 0) {
#pragma unroll
        for (int qi = 0; qi < 2; ++qi) {
            int idx = wn * 64 + qi * 32 + l31;
            u64 m1k = km[qi]; float m1v = kv1[qi], m2 = kv2[qi];
#pragma unroll
            for (int j = 0; j < 3; ++j) {
                u64 ok = sK[j][idx]; float ov = sV1[j][idx], om2 = sV2[j][idx];
                if (ok < m1k) { m2 = fminf(fminf(m2, om2), m1v); m1v = ov; m1k = ok; }
                else m2 = fminf(fminf(m2, om2), ov);
            }
            int tok = n0 + idx;
            slot_m1[((size_t)blockIdx.y << 13) + tok] = m1k;
            slot_d[((size_t)blockIdx.y << 13) + tok] = (_Float16)(m2 - m1v);
        }
    }
}

// ---- combine: merge 32 chunk summaries per token; gap-test; worklist the unsafe ----
__global__ void combine_kernel(const u64* __restrict__ slot_m1, const _Float16* __restrict__ slot_d,
                               u64* __restrict__ wexact, int* __restrict__ worklist,
                               int* __restrict__ nflag) {
    int tok = blockIdx.x * 256 + threadIdx.x;
    u64 g1 = ~0ULL;
    float g1v = 3.4e38f, g2 = 3.4e38f;
    for (int c = 0; c < 32; ++c) {
        u64 k = slot_m1[((size_t)c << 13) + tok];
        float kv = unmono((uint32_t)(k >> 32));
        float v2 = kv + (float)slot_d[((size_t)c << 13) + tok];
        if (k < g1) { g2 = fminf(g2, g1v); g1 = k; g1v = kv; }
        else g2 = fminf(g2, kv);
        g2 = fminf(g2, v2);
    }
    if (g2 - g1v > THR_GAP) wexact[tok] = g1;
    else { int i = atomicAdd(nflag, 1); if (i < 8192) worklist[i] = tok; }
}

// ---- fallback: exact fp32 rescore of flagged tokens over all codes ----
__global__ void fallback_kernel(const float* __restrict__ z, const float* __restrict__ cb,
                                const float* __restrict__ cnorm,
                                const int* __restrict__ worklist, const int* __restrict__ nflag,
                                u64* __restrict__ wexact) {
    int n = *nflag;
    if (n > 8192) n = 8192;
    const int l = threadIdx.x & 63, wv = threadIdx.x >> 6;
    const int cbase = blockIdx.x * 128;
    for (int fi = blockIdx.y; fi < n; fi += gridDim.y) {
        int tok = worklist[fi];
        int b = tok >> 8, t = tok & 255;
        const float* zp = z + ((size_t)b * EMBED_DIM) * T_ + t;
        float zr[8];
#pragma unroll
        for (int j = 0; j < 8; ++j) zr[j] = zp[(size_t)(l * 8 + j) * T_];
        u64 m1 = ~0ULL;
        for (int j = 0; j < 32; ++j) {
            int c = cbase + wv + j * 4;
            const float* cp = cb + (size_t)c * EMBED_DIM + l * 8;
            float4 a = *(const float4*)cp, bb = *(const float4*)(cp + 4);
            float dot = zr[0] * a.x + zr[1] * a.y + zr[2] * a.z + zr[3] * a.w +
                        zr[4] * bb.x + zr[5] * bb.y + zr[6] * bb.z + zr[7] * bb.w;
#pragma unroll
            for (int m = 32; m; m >>= 1) dot += __shfl_xor(dot, m, 64);
            if (l == 0) {
                float s = cnorm[c] - 2.0f * dot;
                u64 key = ((u64)mono(s) << 32) | (uint32_t)c;
                if (key < m1) m1 = key;
            }
        }
        if (l == 0) atomicMin(&wexact[tok], m1);
    }
}

__global__ void gather_kernel(const float* __restrict__ z, const float* __restrict__ cb,
                              const u64* __restrict__ wexact,
                              float* __restrict__ out, int* __restrict__ counts,
                              float* __restrict__ sse_acc) {
    __shared__ unsigned int sIdx[64];
    __shared__ float red[4];
    const int tid = threadIdx.x;
    const int n0 = blockIdx.x * 64;
    const int b = n0 >> 8;
    const int t0 = n0 & 255;
    if (tid < 64) {
        unsigned int idx = (unsigned int)(wexact[n0 + tid] & 0xffffffffULL);
        sIdx[tid] = idx;
        atomicAdd(&counts[idx], 1);
    }
    __syncthreads();
    const int w = tid >> 6;
    const int lane = tid & 63;
    const float* crow = cb + (size_t)sIdx[lane] * EMBED_DIM;
    const size_t base = ((size_t)b * EMBED_DIM) * T_ + (size_t)(t0 + lane);
    float sse = 0.f;
    for (int d = w; d < EMBED_DIM; d += 4) {
        float v = crow[d];
        size_t o = base + (size_t)d * T_;
        float diff = v - z[o];
        out[o] = v;
        sse += diff * diff;
    }
    for (int m = 32; m; m >>= 1) sse += __shfl_xor(sse, m, 64);
    if (lane == 0) red[w] = sse;
    __syncthreads();
    if (tid == 0) atomicAdd(sse_acc, red[0] + red[1] + red[2] + red[3]);
}

__global__ void finalize_kernel(const int* __restrict__ counts,
                                const float* __restrict__ sse_acc,
                                float* __restrict__ out) {
    __shared__ float red[4];
    const int tid = threadIdx.x;
    float e = 0.f;
    for (int k = tid; k < NUM_EMBEDS; k += 256) {
        float p = (float)counts[k] * (1.0f / (float)N_TOK);
        e += p * logf(p + 1e-10f);
    }
    for (int m = 32; m; m >>= 1) e += __shfl_xor(e, m, 64);
    if ((tid & 63) == 0) red[tid >> 6] = e;
    __syncthreads();
    if (tid == 0) {
        float ent = red[0] + red[1] + red[2] + red[3];
        size_t off = (size_t)B_ * EMBED_DIM * T_;
        out[off + 0] = (ALPHA_ * BETA_) * sse_acc[0] / (float)((size_t)N_TOK * EMBED_DIM);
        out[off + 1] = expf(-ent);
    }
}

extern "C" void kernel_launch(void* const* d_in, const int* in_sizes, int n_in,
                              void* d_out, int out_size, void* d_ws, size_t ws_size,
                              hipStream_t stream) {
    const float* z = (const float*)d_in[0];
    const float* cb = (const float*)d_in[1];
    float* out = (float*)d_out;
    char* ws = (char*)d_ws;
    u64* wexact = (u64*)ws;
    float* cnorm = (float*)(ws + 65536);
    int* counts = (int*)(ws + 98304);
    float* sse = (float*)(ws + 131072);
    int* nflag = (int*)(ws + 131076);
    int* worklist = (int*)(ws + 131080);
    u64* slot_m1 = (u64*)(ws + (1ull << 20));
    _Float16* slot_d = (_Float16*)(ws + (5ull << 20));
    _Float16* cb_i = (_Float16*)(ws + (6ull << 20));
    _Float16* zt_i = (_Float16*)(ws + (22ull << 20));

    hipMemsetAsync(wexact, 0xFF, NUM_EMBEDS * sizeof(u64), stream);
    hipMemsetAsync(counts, 0, NUM_EMBEDS * sizeof(int) + 8, stream);  // counts + sse + nflag

    pack_cb_kernel<<<NUM_EMBEDS / 4, 256, 0, stream>>>(cb, cb_i, cnorm);
    pack_z_kernel<<<N_TOK / 64, 256, 0, stream>>>(z, zt_i);
    argmin_kernel<<<dim3(N_TOK / 128, NUM_EMBEDS / 256), 512, 0, stream>>>(cb_i, zt_i, cnorm, slot_m1, slot_d);
    combine_kernel<<<N_TOK / 256, 256, 0, stream>>>(slot_m1, slot_d, wexact, worklist, nflag);
    fallback_kernel<<<dim3(64, 16), 256, 0, stream>>>(z, cb, cnorm, worklist, nflag, wexact);
    gather_kernel<<<N_TOK / 64, 256, 0, stream>>>(z, cb, wexact, out, counts, sse);
    finalize_kernel<<<1, 256, 0, stream>>>(counts, sse, out);
}

// Round 2
// 373.243 us; speedup vs baseline: 1.0087x; 1.0087x over previous
//
#include <hip/hip_runtime.h>
#include <stdint.h>

typedef _Float16 half8 __attribute__((ext_vector_type(8)));
typedef float floatx16 __attribute__((ext_vector_type(16)));
typedef unsigned long long u64;

#define ALPHA_ 1.0f
#define BETA_ 0.25f
#define NUM_EMBEDS 8192
#define EMBED_DIM 512
#define B_ 32
#define T_ 256
#define N_TOK 8192
#define THR_GAP 2e-3f

// ---------------- ws layout (bytes) ----------------
// wexact   @ 0        (64 KB)  u64 packed exact min: monokey<<32 | code
// cnorm    @ 65536    (32 KB)  ||c||^2
// counts   @ 98304    (32 KB)
// sse      @ 131072   (4 B)
// nflag    @ 131076   (4 B)
// worklist @ 131080   (32 KB)
// slot_m1  @ 1  MB    (2 MB)   u64 [32 chunks][8192 tok] block min1 key
// slot_d   @ 5  MB    (512 KB) f16 [32][8192] (min2 - min1) delta
// cb_f     @ 6  MB    (16 MB)  f16 fragment-major codebook
// zt_f     @ 22 MB    (16 MB)  f16 fragment-major -2*z^T
// ---------------------------------------------------
// fragment-major layouts (halves):
//   cb_f: [cb32 chunk][slot = s*4+kk*2+pl (64)][lane (64)][8]   chunk = 32768 halves
//         lane = (row&31) + hf*32 ; slot covers d-group (s, kk, hf-half), plane pl
//   zt_f: [tb128 chunk][slot (64)][q (4)][lane (64)][8]         chunk = 131072 halves
// A wave's MFMA operand load is then  base + slot*512(*4+q*512) + lane*8  -> one
// global_load_dwordx4 per fragment, perfectly coalesced, zero LDS in main loop.

__device__ __forceinline__ uint32_t mono(float s) {
    uint32_t u = __float_as_uint(s);
    return (u & 0x80000000u) ? ~u : (u | 0x80000000u);
}
__device__ __forceinline__ float unmono(uint32_t v) {
    return __uint_as_float((v & 0x80000000u) ? (v ^ 0x80000000u) : ~v);
}

__global__ void pack_cb_kernel(const float* __restrict__ cb, _Float16* __restrict__ cf,
                               float* __restrict__ cnorm) {
    int row = blockIdx.x * 4 + (threadIdx.x >> 6);
    int l = threadIdx.x & 63;
    const float* src = cb + (size_t)row * EMBED_DIM + l * 8;
    float4 v0 = *(const float4*)src;
    float4 v1 = *(const float4*)(src + 4);
    float x[8] = {v0.x, v0.y, v0.z, v0.w, v1.x, v1.y, v1.z, v1.w};
    half8 hh, mm;
    float s = 0.f;
#pragma unroll
    for (int j = 0; j < 8; ++j) {
        s += x[j] * x[j];
        _Float16 hv = (_Float16)x[j];
        hh[j] = hv;
        mm[j] = (_Float16)((x[j] - (float)hv) * 2048.0f);
    }
    // lane l covers d in [8l, 8l+8): s_=l>>2, kk=(l>>1)&1, hf=l&1
    int s_ = l >> 2, kk = (l >> 1) & 1, hfb = l & 1;
    int slot0 = s_ * 4 + kk * 2;
    size_t base = (size_t)(row >> 5) * 32768 + (size_t)slot0 * 512 +
                  (size_t)((row & 31) + hfb * 32) * 8;
    *(half8*)(cf + base) = hh;
    *(half8*)(cf + base + 512) = mm;
#pragma unroll
    for (int d = 32; d; d >>= 1) s += __shfl_xor(s, d, 64);
    if (l == 0) cnorm[row] = s;
}

__global__ void pack_z_kernel(const float* __restrict__ z, _Float16* __restrict__ zf) {
    int tid = threadIdx.x;
    int l = tid & 63, ds = tid >> 6;  // ds 0..3 selects d-subgroup
    int n = blockIdx.x * 64 + l;      // global token
    int b = n >> 8, t = n & 255;
    int kk = ds >> 1, hfb = ds & 1;
    int tb = n >> 7, q = (n >> 5) & 3;
    size_t lanebase = (size_t)tb * 131072 + (size_t)q * 512 +
                      (size_t)((n & 31) + hfb * 32) * 8;
    for (int g = 0; g < 16; ++g) {
        int d0 = g * 32 + ds * 8;  // s = g, d-group = ds
        const float* src = z + ((size_t)b * EMBED_DIM + d0) * T_ + t;
        half8 hh, mm;
#pragma unroll
        for (int j = 0; j < 8; ++j) {
            float x = -2.0f * src[(size_t)j * T_];
            _Float16 hv = (_Float16)x;
            hh[j] = hv;
            mm[j] = (_Float16)((x - (float)hv) * 2048.0f);
        }
        int slot0 = g * 4 + kk * 2;
        _Float16* dst = zf + lanebase + (size_t)slot0 * 2048;
        *(half8*)dst = hh;
        *(half8*)(dst + 2048) = mm;
    }
}

// ---- pass 1: 2-plane argmin GEMM, barrier-free main loop.
//      Block = 8 independent waves sharing one 128-token slice; each wave owns
//      32 codes (1x4 of 32x32 tiles). Operands load global->reg fragment-major,
//      double-buffered in registers; no LDS, no syncs until the epilogue merge. ----
#define MFMA16(a, b, c) __builtin_amdgcn_mfma_f32_32x32x16_f16(a, b, c, 0, 0, 0)

#define LOADSET(X, hs)                                                              \
    X##Ah = *(const half8*)(Ab + ((hs)*2 + 0) * 512 + lane8);                       \
    X##Am = *(const half8*)(Ab + ((hs)*2 + 1) * 512 + lane8);                       \
    _Pragma("unroll") for (int q_ = 0; q_ < 4; ++q_) {                              \
        X##Bh[q_] = *(const half8*)(Bb + (((hs)*2 + 0) * 4 + q_) * 512 + lane8);    \
        X##Bm[q_] = *(const half8*)(Bb + (((hs)*2 + 1) * 4 + q_) * 512 + lane8);    \
    }

#define MFMASET(X)                                                                  \
    _Pragma("unroll") for (int q_ = 0; q_ < 4; ++q_)                                \
        acc1[q_] = MFMA16(X##Ah, X##Bh[q_], acc1[q_]);                              \
    _Pragma("unroll") for (int q_ = 0; q_ < 4; ++q_)                                \
        acc2[q_] = MFMA16(X##Ah, X##Bm[q_], acc2[q_]);                              \
    _Pragma("unroll") for (int q_ = 0; q_ < 4; ++q_)                                \
        acc2[q_] = MFMA16(X##Am, X##Bh[q_], acc2[q_]);

__global__ __launch_bounds__(512, 2) void argmin_kernel(
    const _Float16* __restrict__ cb_f, const _Float16* __restrict__ zt_f,
    const float* __restrict__ cnorm, u64* __restrict__ slot_m1,
    _Float16* __restrict__ slot_d) {
    __shared__ u64 sK[8][128];
    __shared__ float sV1[8][128], sV2[8][128];

    const int tid = threadIdx.x;
    const int l = tid & 63;
    const int wv = tid >> 6;  // 0..7: wave's code chunk within group
    const int l31 = l & 31;
    const int hf = l >> 5;
    const int tb = blockIdx.x;           // 128-token slice
    const int c0 = blockIdx.y * 256;     // 256-code group
    const int cb32 = blockIdx.y * 8 + wv;

    const _Float16* Ab = cb_f + (size_t)cb32 * 32768;
    const _Float16* Bb = zt_f + (size_t)tb * 131072;
    const int lane8 = l * 8;

    floatx16 acc1[4], acc2[4];
#pragma unroll
    for (int q = 0; q < 4; ++q)
#pragma unroll
        for (int r = 0; r < 16; ++r) { acc1[q][r] = 0.f; acc2[q][r] = 0.f; }

    half8 cAh, cAm, cBh[4], cBm[4];
    half8 nAh, nAm, nBh[4], nBm[4];

    // register-double-buffered K loop: 32 half-steps of K=16
    LOADSET(c, 0);
    for (int hs = 0; hs < 30; hs += 2) {
        LOADSET(n, hs + 1);
        MFMASET(c);
        LOADSET(c, hs + 2);
        MFMASET(n);
    }
    LOADSET(n, 31);
    MFMASET(c);  // hs = 30
    MFMASET(n);  // hs = 31

    // epilogue: lane covers 16 rows (hf half) of the wave's 32 codes, 4 tokens (q)
    const int cb0 = c0 + wv * 32;
    u64 km[4]; float kv1[4], kv2[4];
#pragma unroll
    for (int q = 0; q < 4; ++q) {
        u64 m1k = ~0ULL;
        float m1v = 3.4e38f, m2 = 3.4e38f;
#pragma unroll
        for (int g = 0; g < 4; ++g) {
            const int cb4 = cb0 + g * 8 + hf * 4;
            float4 cn = *(const float4*)(cnorm + cb4);
            float sv[4] = {cn.x + acc1[q][g * 4 + 0] + acc2[q][g * 4 + 0] * (1.0f / 2048.0f),
                           cn.y + acc1[q][g * 4 + 1] + acc2[q][g * 4 + 1] * (1.0f / 2048.0f),
                           cn.z + acc1[q][g * 4 + 2] + acc2[q][g * 4 + 2] * (1.0f / 2048.0f),
                           cn.w + acc1[q][g * 4 + 3] + acc2[q][g * 4 + 3] * (1.0f / 2048.0f)};
#pragma unroll
            for (int r = 0; r < 4; ++r) {
                u64 key = ((u64)mono(sv[r]) << 32) | (uint32_t)(cb4 + r);
                if (key < m1k) { m2 = m1v; m1v = sv[r]; m1k = key; }
                else m2 = fminf(m2, sv[r]);
            }
        }
        // merge the hf pair (same token, other 16 rows)
        u64 ok = __shfl_xor(m1k, 32, 64);
        float ov = __shfl_xor(m1v, 32, 64);
        float om2 = __shfl_xor(m2, 32, 64);
        if (ok < m1k) { m2 = fminf(fminf(m2, om2), m1v); m1v = ov; m1k = ok; }
        else m2 = fminf(fminf(m2, om2), ov);
        km[q] = m1k; kv1[q] = m1v; kv2[q] = m2;
    }
    if (hf == 0) {
#pragma unroll
        for (int q = 0; q < 4; ++q) {
            int idx = q * 32 + l31;
            sK[wv][idx] = km[q]; sV1[wv][idx] = kv1[q]; sV2[wv][idx] = kv2[q];
        }
    }
    __syncthreads();
    if (tid < 128) {
        u64 m1k = ~0ULL;
        float m1v = 3.4e38f, m2 = 3.4e38f;
#pragma unroll
        for (int w = 0; w < 8; ++w) {
            u64 ok = sK[w][tid]; float ov = sV1[w][tid], om2 = sV2[w][tid];
            if (ok < m1k) { m2 = fminf(fminf(m2, om2), m1v); m1v = ov; m1k = ok; }
            else m2 = fminf(fminf(m2, om2), ov);
        }
        int tok = tb * 128 + tid;
        slot_m1[((size_t)blockIdx.y << 13) + tok] = m1k;
        slot_d[((size_t)blockIdx.y << 13) + tok] = (_Float16)(m2 - m1v);
    }
}

// ---- combine: merge 32 chunk summaries per token; gap-test; worklist the unsafe ----
__global__ void combine_kernel(const u64* __restrict__ slot_m1, const _Float16* __restrict__ slot_d,
                               u64* __restrict__ wexact, int* __restrict__ worklist,
                               int* __restrict__ nflag) {
    int tok = blockIdx.x * 256 + threadIdx.x;
    u64 g1 = ~0ULL;
    float g1v = 3.4e38f, g2 = 3.4e38f;
    for (int c = 0; c < 32; ++c) {
        u64 k = slot_m1[((size_t)c << 13) + tok];
        float kv = unmono((uint32_t)(k >> 32));
        float v2 = kv + (float)slot_d[((size_t)c << 13) + tok];
        if (k < g1) { g2 = fminf(g2, g1v); g1 = k; g1v = kv; }
        else g2 = fminf(g2, kv);
        g2 = fminf(g2, v2);
    }
    if (g2 - g1v > THR_GAP) wexact[tok] = g1;
    else { int i = atomicAdd(nflag, 1); if (i < 8192) worklist[i] = tok; }
}

// ---- fallback: exact fp32 rescore of flagged tokens over all codes ----
__global__ void fallback_kernel(const float* __restrict__ z, const float* __restrict__ cb,
                                const float* __restrict__ cnorm,
                                const int* __restrict__ worklist, const int* __restrict__ nflag,
                                u64* __restrict__ wexact) {
    int n = *nflag;
    if (n > 8192) n = 8192;
    const int l = threadIdx.x & 63, wv = threadIdx.x >> 6;
    const int cbase = blockIdx.x * 128;
    for (int fi = blockIdx.y; fi < n; fi += gridDim.y) {
        int tok = worklist[fi];
        int b = tok >> 8, t = tok & 255;
        const float* zp = z + ((size_t)b * EMBED_DIM) * T_ + t;
        float zr[8];
#pragma unroll
        for (int j = 0; j < 8; ++j) zr[j] = zp[(size_t)(l * 8 + j) * T_];
        u64 m1 = ~0ULL;
        for (int j = 0; j < 32; ++j) {
            int c = cbase + wv + j * 4;
            const float* cp = cb + (size_t)c * EMBED_DIM + l * 8;
            float4 a = *(const float4*)cp, bb = *(const float4*)(cp + 4);
            float dot = zr[0] * a.x + zr[1] * a.y + zr[2] * a.z + zr[3] * a.w +
                        zr[4] * bb.x + zr[5] * bb.y + zr[6] * bb.z + zr[7] * bb.w;
#pragma unroll
            for (int m = 32; m; m >>= 1) dot += __shfl_xor(dot, m, 64);
            if (l == 0) {
                float s = cnorm[c] - 2.0f * dot;
                u64 key = ((u64)mono(s) << 32) | (uint32_t)c;
                if (key < m1) m1 = key;
            }
        }
        if (l == 0) atomicMin(&wexact[tok], m1);
    }
}

__global__ void gather_kernel(const float* __restrict__ z, const float* __restrict__ cb,
                              const u64* __restrict__ wexact,
                              float* __restrict__ out, int* __restrict__ counts,
                              float* __restrict__ sse_acc) {
    __shared__ unsigned int sIdx[64];
    __shared__ float red[4];
    const int tid = threadIdx.x;
    const int n0 = blockIdx.x * 64;
    const int b = n0 >> 8;
    const int t0 = n0 & 255;
    if (tid < 64) {
        unsigned int idx = (unsigned int)(wexact[n0 + tid] & 0xffffffffULL);
        sIdx[tid] = idx;
        atomicAdd(&counts[idx], 1);
    }
    __syncthreads();
    const int w = tid >> 6;
    const int lane = tid & 63;
    const float* crow = cb + (size_t)sIdx[lane] * EMBED_DIM;
    const size_t base = ((size_t)b * EMBED_DIM) * T_ + (size_t)(t0 + lane);
    float sse = 0.f;
    for (int d = w; d < EMBED_DIM; d += 4) {
        float v = crow[d];
        size_t o = base + (size_t)d * T_;
        float diff = v - z[o];
        out[o] = v;
        sse += diff * diff;
    }
    for (int m = 32; m; m >>= 1) sse += __shfl_xor(sse, m, 64);
    if (lane == 0) red[w] = sse;
    __syncthreads();
    if (tid == 0) atomicAdd(sse_acc, red[0] + red[1] + red[2] + red[3]);
}

__global__ void finalize_kernel(const int* __restrict__ counts,
                                const float* __restrict__ sse_acc,
                                float* __restrict__ out) {
    __shared__ float red[4];
    const int tid = threadIdx.x;
    float e = 0.f;
    for (int k = tid; k < NUM_EMBEDS; k += 256) {
        float p = (float)counts[k] * (1.0f / (float)N_TOK);
        e += p * logf(p + 1e-10f);
    }
    for (int m = 32; m; m >>= 1) e += __shfl_xor(e, m, 64);
    if ((tid & 63) == 0) red[tid >> 6] = e;
    __syncthreads();
    if (tid == 0) {
        float ent = red[0] + red[1] + red[2] + red[3];
        size_t off = (size_t)B_ * EMBED_DIM * T_;
        out[off + 0] = (ALPHA_ * BETA_) * sse_acc[0] / (float)((size_t)N_TOK * EMBED_DIM);
        out[off + 1] = expf(-ent);
    }
}

extern "C" void kernel_launch(void* const* d_in, const int* in_sizes, int n_in,
                              void* d_out, int out_size, void* d_ws, size_t ws_size,
                              hipStream_t stream) {
    const float* z = (const float*)d_in[0];
    const float* cb = (const float*)d_in[1];
    float* out = (float*)d_out;
    char* ws = (char*)d_ws;
    u64* wexact = (u64*)ws;
    float* cnorm = (float*)(ws + 65536);
    int* counts = (int*)(ws + 98304);
    float* sse = (float*)(ws + 131072);
    int* nflag = (int*)(ws + 131076);
    int* worklist = (int*)(ws + 131080);
    u64* slot_m1 = (u64*)(ws + (1ull << 20));
    _Float16* slot_d = (_Float16*)(ws + (5ull << 20));
    _Float16* cb_f = (_Float16*)(ws + (6ull << 20));
    _Float16* zt_f = (_Float16*)(ws + (22ull << 20));

    hipMemsetAsync(wexact, 0xFF, NUM_EMBEDS * sizeof(u64), stream);
    hipMemsetAsync(counts, 0, NUM_EMBEDS * sizeof(int) + 8, stream);  // counts + sse + nflag

    pack_cb_kernel<<<NUM_EMBEDS / 4, 256, 0, stream>>>(cb, cb_f, cnorm);
    pack_z_kernel<<<N_TOK / 64, 256, 0, stream>>>(z, zt_f);
    argmin_kernel<<<dim3(N_TOK / 128, NUM_EMBEDS / 256), 512, 0, stream>>>(cb_f, zt_f, cnorm, slot_m1, slot_d);
    combine_kernel<<<N_TOK / 256, 256, 0, stream>>>(slot_m1, slot_d, wexact, worklist, nflag);
    fallback_kernel<<<dim3(64, 16), 256, 0, stream>>>(z, cb, cnorm, worklist, nflag, wexact);
    gather_kernel<<<N_TOK / 64, 256, 0, stream>>>(z, cb, wexact, out, counts, sse);
    finalize_kernel<<<1, 256, 0, stream>>>(counts, sse, out);
}